// Round 15
// baseline (247.420 us; speedup 1.0000x reference)
//
#include <hip/hip_runtime.h>
#include <hip/hip_bf16.h>

#define NGRAPHS 64
#define RANGE 8192
#define RSHIFT 13
#define CHUNKS 32
#define OCHUNKS 8

typedef unsigned short u16;
typedef unsigned int u32;
typedef unsigned long long u64;
typedef unsigned short bf16_t;
using s8v = __attribute__((ext_vector_type(8))) short;   // 8 bf16 (4 VGPRs)
using f4v = __attribute__((ext_vector_type(4))) float;   // MFMA accumulator

__device__ inline float bf2f(bf16_t u) { return __uint_as_float(((unsigned)u) << 16); }
__device__ inline bf16_t f2bf(float f) {
    unsigned x = __float_as_uint(f);
    return (bf16_t)((x + 0x7fffu + ((x >> 16) & 1u)) >> 16);  // RNE
}
__device__ inline void acc4(u64 v, float& a, float& b, float& c, float& d) {
    u32 lo = (u32)v, hi = (u32)(v >> 32);
    a += __uint_as_float(lo << 16);
    b += __uint_as_float(lo & 0xFFFF0000u);
    c += __uint_as_float(hi << 16);
    d += __uint_as_float(hi & 0xFFFF0000u);
}

// ============ init: bucket cursors (base r*E), gsum zero, ticket zero ============
__global__ void k_init(int* __restrict__ dcur, int* __restrict__ scur,
                       float* __restrict__ gsum, int* __restrict__ ticket, int E) {
    int t = threadIdx.x;
    if (t < 16) { dcur[t] = t * E; scur[t] = t * E; }
    if (t == 0) *ticket = 0;
    gsum[t] = 0.0f;
}

// ============ partition edges by dst-range (and src by src-range); LDS local rank ============
__global__ void k_part(const int* __restrict__ src, const int* __restrict__ dst,
                       int* __restrict__ dcur, int* __restrict__ scur,
                       u32* __restrict__ ebuf, u16* __restrict__ sbuf, int nr, int E) {
    __shared__ int ldc[16], lsc[16], gdb[16], gsb[16];
    int tid = threadIdx.x;
    if (tid < 16) { ldc[tid] = 0; lsc[tid] = 0; }
    __syncthreads();
    int e4 = (blockIdx.x * 256 + tid) * 4;
    int s[4], d[4], pd[4], ps[4];
    int cnt = 0;
    if (e4 + 4 <= E) {
        int4 dv = *(const int4*)&dst[e4];
        int4 sv = *(const int4*)&src[e4];
        s[0] = sv.x; s[1] = sv.y; s[2] = sv.z; s[3] = sv.w;
        d[0] = dv.x; d[1] = dv.y; d[2] = dv.z; d[3] = dv.w;
        cnt = 4;
    } else {
        for (int e = e4; e < E; ++e) { s[cnt] = src[e]; d[cnt] = dst[e]; ++cnt; }
    }
    for (int i = 0; i < cnt; ++i) {
        pd[i] = atomicAdd(&ldc[d[i] >> RSHIFT], 1);   // LDS local rank
        ps[i] = atomicAdd(&lsc[s[i] >> RSHIFT], 1);
    }
    __syncthreads();
    if (tid < nr) {
        gdb[tid] = atomicAdd(&dcur[tid], ldc[tid]);   // ~14 global atomics/block
        gsb[tid] = atomicAdd(&scur[tid], lsc[tid]);
    }
    __syncthreads();
    for (int i = 0; i < cnt; ++i) {
        int db = d[i] >> RSHIFT, sb = s[i] >> RSHIFT;
        ebuf[gdb[db] + pd[i]] = ((u32)s[i] << 16) | (u32)d[i];
        sbuf[gsb[sb] + ps[i]] = (u16)s[i];
    }
}

// ============ histogram: in (dst, CHUNKS copies) then out (src, OCHUNKS copies) ============
__global__ void k_hist(const u32* __restrict__ ebuf, const u16* __restrict__ sbuf,
                       const int* __restrict__ dcur, const int* __restrict__ scur,
                       u16* __restrict__ cntC_in, u16* __restrict__ cntC_out,
                       int nr, int n, int E) {
    __shared__ int hist[RANGE];
    int tid = threadIdx.x, bid = blockIdx.x;
    int type, r, c, nchunk;
    if (bid < nr * CHUNKS) {
        type = 0; r = bid / CHUNKS; c = bid - r * CHUNKS; nchunk = CHUNKS;
    } else {
        int rem = bid - nr * CHUNKS;
        type = 1; r = rem / OCHUNKS; c = rem - r * OCHUNKS; nchunk = OCHUNKS;
    }
    for (int i = tid; i < RANGE; i += 256) hist[i] = 0;
    __syncthreads();
    int lo = r * RANGE;
    int seg0 = r * E;
    int seg1 = type ? scur[r] : dcur[r];
    int sz = seg1 - seg0;
    int ce0 = seg0 + (int)((long long)sz * c / nchunk);
    int ce1 = seg0 + (int)((long long)sz * (c + 1) / nchunk);
    int e = ce0 + tid;
    if (type == 0) {
        for (; e + 768 < ce1; e += 1024) {
            int k0 = ebuf[e] & 0xFFFF, k1 = ebuf[e + 256] & 0xFFFF;
            int k2 = ebuf[e + 512] & 0xFFFF, k3 = ebuf[e + 768] & 0xFFFF;
            atomicAdd(&hist[k0 - lo], 1); atomicAdd(&hist[k1 - lo], 1);
            atomicAdd(&hist[k2 - lo], 1); atomicAdd(&hist[k3 - lo], 1);
        }
        for (; e < ce1; e += 256) atomicAdd(&hist[(ebuf[e] & 0xFFFF) - lo], 1);
    } else {
        for (; e + 768 < ce1; e += 1024) {
            int k0 = sbuf[e], k1 = sbuf[e + 256], k2 = sbuf[e + 512], k3 = sbuf[e + 768];
            atomicAdd(&hist[k0 - lo], 1); atomicAdd(&hist[k1 - lo], 1);
            atomicAdd(&hist[k2 - lo], 1); atomicAdd(&hist[k3 - lo], 1);
        }
        for (; e < ce1; e += 256) atomicAdd(&hist[(int)sbuf[e] - lo], 1);
    }
    __syncthreads();
    int hi = min(n - lo, RANGE);
    u16* __restrict__ outb = (type ? cntC_out : cntC_in) + (size_t)c * n + lo;
    for (int i = tid; i < hi; i += 256) outb[i] = (u16)hist[i];
}

__device__ inline int block_excl_scan(int v, int tid, int* wavesums, int* block_total) {
    int lane = tid & 63, wave = tid >> 6;
    int incl = v;
    #pragma unroll
    for (int off = 1; off < 64; off <<= 1) {
        int t = __shfl_up(incl, off);
        if (lane >= off) incl += t;
    }
    if (lane == 63) wavesums[wave] = incl;
    __syncthreads();
    int woff = 0;
    #pragma unroll
    for (int w = 0; w < 4; ++w) if (w < wave) woff += wavesums[w];
    *block_total = wavesums[0] + wavesums[1] + wavesums[2] + wavesums[3];
    return incl + woff - v;
}

__global__ void k_scan1(const u16* __restrict__ cntC_in,
                        int* __restrict__ rowptr, int* __restrict__ blocksums, int n) {
    __shared__ int wavesums[4];
    int tid = threadIdx.x;
    int idx = blockIdx.x * 256 + tid;
    int v = 0;
    if (idx < n) {
        #pragma unroll
        for (int k = 0; k < CHUNKS; ++k) v += (int)cntC_in[(size_t)k * n + idx];
    }
    int total;
    int excl = block_excl_scan(v, tid, wavesums, &total);
    if (idx < n) rowptr[idx] = excl;
    if (tid == 0) blocksums[blockIdx.x] = total;
}

// scan3 with scan2 folded in (nb <= 256); in-degree derived from cursor-base walk
__global__ void k_scan3(int* __restrict__ rowptr, const int* __restrict__ blocksums,
                        const u16* __restrict__ cntC_in, const u16* __restrict__ cntC_out,
                        int* __restrict__ cursorC,
                        float* __restrict__ norm_src, float* __restrict__ norm_dst,
                        float* __restrict__ vsrc, int nb, int n, int E) {
    __shared__ int wavesums[4];
    __shared__ int sbs[256];
    int tid = threadIdx.x;
    int bv = (tid < nb) ? blocksums[tid] : 0;
    int total;
    int bexcl = block_excl_scan(bv, tid, wavesums, &total);
    sbs[tid] = bexcl;
    __syncthreads();
    int blockoff = sbs[blockIdx.x];

    int idx = blockIdx.x * 256 + tid;
    if (idx < n) {
        int base0 = rowptr[idx] + blockoff;
        int base = base0;
        rowptr[idx] = base0;
        #pragma unroll
        for (int k = 0; k < CHUNKS; ++k) {
            cursorC[(size_t)k * n + idx] = base;
            base += (int)cntC_in[(size_t)k * n + idx];
        }
        int dout = 0;
        #pragma unroll
        for (int k = 0; k < OCHUNKS; ++k) dout += (int)cntC_out[(size_t)k * n + idx];
        float di = (float)(base - base0);
        float ns = rsqrtf(fmaxf((float)dout, 1.0f));
        norm_src[idx] = ns;
        norm_dst[idx] = rsqrtf(fmaxf(di, 1.0f));
        vsrc[idx] = di * ns;
    }
    if (idx == 0) rowptr[n] = E;
}

__global__ void k_fillv2(const u32* __restrict__ ebuf, const int* __restrict__ dcur,
                         const int* __restrict__ cursorC, u16* __restrict__ colsrc,
                         int nr, int n, int E) {
    __shared__ int cur[RANGE];
    int tid = threadIdx.x, bid = blockIdx.x;
    int r = bid / CHUNKS, c = bid - r * CHUNKS;
    int lo = r * RANGE, hi = min(n - lo, RANGE);
    for (int i = tid; i < hi; i += 256) cur[i] = cursorC[(size_t)c * n + lo + i];
    __syncthreads();
    int seg0 = r * E, seg1 = dcur[r];
    int sz = seg1 - seg0;
    int ce0 = seg0 + (int)((long long)sz * c / CHUNKS);
    int ce1 = seg0 + (int)((long long)sz * (c + 1) / CHUNKS);
    int e = ce0 + tid;
    for (; e + 768 < ce1; e += 1024) {
        u32 v0 = ebuf[e], v1 = ebuf[e + 256], v2 = ebuf[e + 512], v3 = ebuf[e + 768];
        colsrc[atomicAdd(&cur[(v0 & 0xFFFF) - lo], 1)] = (u16)(v0 >> 16);
        colsrc[atomicAdd(&cur[(v1 & 0xFFFF) - lo], 1)] = (u16)(v1 >> 16);
        colsrc[atomicAdd(&cur[(v2 & 0xFFFF) - lo], 1)] = (u16)(v2 >> 16);
        colsrc[atomicAdd(&cur[(v3 & 0xFFFF) - lo], 1)] = (u16)(v3 >> 16);
    }
    for (; e < ce1; e += 256) {
        u32 v = ebuf[e];
        colsrc[atomicAdd(&cur[(v & 0xFFFF) - lo], 1)] = (u16)(v >> 16);
    }
}

// ============ layer 0: quarter-wave per node, u64 feat stores ============
__global__ void k_layer0(const int* __restrict__ rowptr, const u16* __restrict__ colsrc,
                         const float* __restrict__ vsrc, const float* __restrict__ norm_dst,
                         const float* __restrict__ norm_src,
                         const float* __restrict__ W0, const float* __restrict__ b0,
                         bf16_t* __restrict__ out, int n) {
    int wave = threadIdx.x >> 6, lane = threadIdx.x & 63;
    int qw = lane >> 4, f = lane & 15;
    int i = blockIdx.x * 16 + wave * 4 + qw;
    if (i >= n) return;
    int p0 = rowptr[i], pe = rowptr[i + 1];
    float s = 0.0f;
    for (int p = p0 + f; p < pe; p += 16) s += vsrc[colsrc[p]];
    #pragma unroll
    for (int off = 1; off < 16; off <<= 1) s += __shfl_xor(s, off);
    float nd = norm_dst[i], ns = norm_src[i];
    float4 w = ((const float4*)W0)[f];
    float4 bb = ((const float4*)b0)[f];
    float a = s * nd;
    float v0 = fmaxf(a * w.x + bb.x, 0.0f) * ns;
    float v1 = fmaxf(a * w.y + bb.y, 0.0f) * ns;
    float v2 = fmaxf(a * w.z + bb.z, 0.0f) * ns;
    float v3 = fmaxf(a * w.w + bb.w, 0.0f) * ns;
    u32 plo = ((u32)f2bf(v1) << 16) | (u32)f2bf(v0);
    u32 phi = ((u32)f2bf(v3) << 16) | (u32)f2bf(v2);
    *(u64*)&out[(size_t)i * 64 + f * 4] = ((u64)phi << 32) | plo;
}

// ============ FUSED gather -> LDS A-strip -> MFMA dense ============
// FUSE_DOT=1: per-graph partial sums -> gsum atomics; LAST block (ticket) finalizes out.
template <int FUSE_DOT>
__global__ __launch_bounds__(256, 4)
void k_fgd(const int* __restrict__ rowptr, const u16* __restrict__ colsrc,
           const bf16_t* __restrict__ hin, const float* __restrict__ norm_dst,
           const float* __restrict__ norm_src,
           const float* __restrict__ W, const float* __restrict__ b,
           const float* __restrict__ Wr, const int* __restrict__ n2g,
           bf16_t* __restrict__ hout, float* __restrict__ gsum,
           int* __restrict__ ticket, const float* __restrict__ br,
           float* __restrict__ out, int n) {
    __shared__ bf16_t Wbf[64 * 64];
    __shared__ float bs[64];
    __shared__ u32 astrip[64 * 36];   // 64 rows, stride 36 u32 = 144 B
    __shared__ float gacc[64];
    __shared__ int islast;
    int tid = threadIdx.x;
    #pragma unroll
    for (int it = 0; it < 16; ++it) {
        int idx = tid + it * 256;
        Wbf[idx] = f2bf(W[idx]);
    }
    if (tid < 64) { bs[tid] = b[tid]; if (FUSE_DOT) gacc[tid] = 0.0f; }
    __syncthreads();

    int wave = tid >> 6, lane = tid & 63;
    int quad = lane >> 4, l16 = lane & 15;
    int qw = lane >> 4, f = lane & 15, qb = qw << 4;

    int m0 = (blockIdx.x * 4 + wave) * 16;
    bool active = (m0 < n);
    if (!FUSE_DOT && !active) return;

    if (active) {
        // B fragments from LDS (one-time)
        s8v bfrag[4][2];
        #pragma unroll
        for (int t = 0; t < 4; ++t)
            #pragma unroll
            for (int c = 0; c < 2; ++c)
                #pragma unroll
                for (int jj = 0; jj < 8; ++jj)
                    bfrag[t][c][jj] = (short)Wbf[(c * 32 + qw * 8 + jj) * 64 + t * 16 + l16];

        const u64* __restrict__ hp = (const u64*)hin;  // row c -> c*16 + f

        // gather 16 rows, 4 at a time (quarter-waves independent)
        for (int t = 0; t < 16; t += 4) {
            int i = m0 + t + qw;
            int p0 = 0, deg = 0;
            if (i < n) { p0 = rowptr[i]; deg = rowptr[i + 1] - p0; }
            float s0 = 0.f, s1 = 0.f, s2 = 0.f, s3 = 0.f;
            float t0 = 0.f, t1 = 0.f, t2 = 0.f, t3 = 0.f;
            for (int cb = 0; cb < deg; cb += 16) {
                int m = min(16, deg - cb);
                int col = (f < m) ? (int)colsrc[p0 + cb + f] : 0;
                int e = 0;
                for (; e + 8 <= m; e += 8) {
                    int c0 = __shfl(col, qb + e),     c1 = __shfl(col, qb + e + 1);
                    int c2 = __shfl(col, qb + e + 2), c3 = __shfl(col, qb + e + 3);
                    int c4 = __shfl(col, qb + e + 4), c5 = __shfl(col, qb + e + 5);
                    int c6 = __shfl(col, qb + e + 6), c7 = __shfl(col, qb + e + 7);
                    u64 v0 = hp[c0 * 16 + f], v1 = hp[c1 * 16 + f];
                    u64 v2 = hp[c2 * 16 + f], v3 = hp[c3 * 16 + f];
                    u64 v4 = hp[c4 * 16 + f], v5 = hp[c5 * 16 + f];
                    u64 v6 = hp[c6 * 16 + f], v7 = hp[c7 * 16 + f];
                    acc4(v0, s0, s1, s2, s3); acc4(v1, t0, t1, t2, t3);
                    acc4(v2, s0, s1, s2, s3); acc4(v3, t0, t1, t2, t3);
                    acc4(v4, s0, s1, s2, s3); acc4(v5, t0, t1, t2, t3);
                    acc4(v6, s0, s1, s2, s3); acc4(v7, t0, t1, t2, t3);
                }
                for (; e < m; ++e) {
                    int c = __shfl(col, qb + e);
                    acc4(hp[c * 16 + f], s0, s1, s2, s3);
                }
            }
            u64 packed = 0;
            if (i < n) {
                float nd = norm_dst[i];
                float f0 = (s0 + t0) * nd, f1 = (s1 + t1) * nd;
                float f2 = (s2 + t2) * nd, f3 = (s3 + t3) * nd;
                u32 plo = ((u32)f2bf(f1) << 16) | (u32)f2bf(f0);
                u32 phi = ((u32)f2bf(f3) << 16) | (u32)f2bf(f2);
                packed = ((u64)phi << 32) | plo;
            }
            *(u64*)&astrip[(wave * 16 + t + qw) * 36 + f * 2] = packed;
        }
        asm volatile("s_waitcnt lgkmcnt(0)" ::: "memory");  // wave-local LDS RAW fence

        const char* ap = (const char*)astrip + (wave * 16 + l16) * 144 + quad * 16;
        s8v a0 = *(const s8v*)ap;
        s8v a1 = *(const s8v*)(ap + 64);

        f4v acc[4];
        #pragma unroll
        for (int t = 0; t < 4; ++t) { acc[t][0] = 0.f; acc[t][1] = 0.f; acc[t][2] = 0.f; acc[t][3] = 0.f; }
        #pragma unroll
        for (int t = 0; t < 4; ++t) {
            acc[t] = __builtin_amdgcn_mfma_f32_16x16x32_bf16(a0, bfrag[t][0], acc[t], 0, 0, 0);
            acc[t] = __builtin_amdgcn_mfma_f32_16x16x32_bf16(a1, bfrag[t][1], acc[t], 0, 0, 0);
        }

        if (FUSE_DOT) {
            float p0 = 0.f, p1 = 0.f, p2 = 0.f, p3 = 0.f;
            #pragma unroll
            for (int t = 0; t < 4; ++t) {
                float wr = Wr[t * 16 + l16];
                float bias = bs[t * 16 + l16];
                p0 = fmaf(fmaxf(acc[t][0] + bias, 0.f), wr, p0);
                p1 = fmaf(fmaxf(acc[t][1] + bias, 0.f), wr, p1);
                p2 = fmaf(fmaxf(acc[t][2] + bias, 0.f), wr, p2);
                p3 = fmaf(fmaxf(acc[t][3] + bias, 0.f), wr, p3);
            }
            float pr[4] = {p0, p1, p2, p3};
            #pragma unroll
            for (int r = 0; r < 4; ++r) {
                float v = pr[r];
                v += __shfl_xor(v, 1); v += __shfl_xor(v, 2);
                v += __shfl_xor(v, 4); v += __shfl_xor(v, 8);
                int i = m0 + quad * 4 + r;
                if (l16 == 0 && i < n) atomicAdd(&gacc[n2g[i]], v);  // LDS atomic
            }
        } else {
            float ns[4];
            #pragma unroll
            for (int r = 0; r < 4; ++r) {
                int i = m0 + quad * 4 + r;
                ns[r] = norm_src[i < n ? i : n - 1];
            }
            #pragma unroll
            for (int t = 0; t < 4; ++t) {
                float bias = bs[t * 16 + l16];
                #pragma unroll
                for (int r = 0; r < 4; ++r) {
                    int i = m0 + quad * 4 + r;
                    if (i < n) {
                        float v = fmaxf(acc[t][r] + bias, 0.f) * ns[r];
                        hout[(size_t)i * 64 + t * 16 + l16] = f2bf(v);
                    }
                }
            }
        }
    }

    if (FUSE_DOT) {
        __syncthreads();
        if (tid < 64) {
            float v = gacc[tid];
            if (v != 0.0f) atomicAdd(&gsum[tid], v);   // ~2 nonzero graphs/block
        }
        __threadfence();
        __syncthreads();
        if (tid == 0) {
            int t = atomicAdd(ticket, 1);
            islast = (t == (int)gridDim.x - 1) ? 1 : 0;
        }
        __syncthreads();
        if (islast && tid < 64) {
            int g = tid;
            int lo = 0, hi = n;
            while (lo < hi) { int mid = (lo + hi) >> 1; if (n2g[mid] < g) lo = mid + 1; else hi = mid; }
            int lo2 = lo, hi2 = n, g1 = g + 1;
            while (lo2 < hi2) { int mid = (lo2 + hi2) >> 1; if (n2g[mid] < g1) lo2 = mid + 1; else hi2 = mid; }
            float S = atomicAdd(&gsum[g], 0.0f);  // memory-side read (coherence-safe)
            out[g] = S / fmaxf((float)(lo2 - lo), 1.0f) + br[0];
        }
    }
}

extern "C" void kernel_launch(void* const* d_in, const int* in_sizes, int n_in,
                              void* d_out, int out_size, void* d_ws, size_t ws_size,
                              hipStream_t stream) {
    const int* src = (const int*)d_in[0];
    const int* dst = (const int*)d_in[1];
    const int* n2g = (const int*)d_in[2];
    const float* W0 = (const float*)d_in[3];
    const float* b0 = (const float*)d_in[4];
    const float* W1 = (const float*)d_in[5];
    const float* b1 = (const float*)d_in[6];
    const float* W2 = (const float*)d_in[7];
    const float* b2 = (const float*)d_in[8];
    const float* Wr = (const float*)d_in[9];
    const float* br = (const float*)d_in[10];
    float* out = (float*)d_out;

    int E = in_sizes[0];
    int n = in_sizes[2];               // 50000 (< 65536: u16 packing valid)
    int nb = (n + 255) / 256;          // 196 (<= 256 for merged scan)
    int nr = (n + RANGE - 1) / RANGE;  // 7

    char* base = (char*)d_ws;
    size_t off = 0;
    auto alloc = [&](size_t bytes) -> void* {
        off = (off + 255) & ~(size_t)255;
        void* p = base + off;
        off += bytes;
        return p;
    };
    int* meta = (int*)alloc(64 * sizeof(int));
    int* dcur = meta;          // 16 (cursor; base r*E)
    int* scur = meta + 16;     // 16
    int* ticket = meta + 32;   // 1
    float* gsum = (float*)alloc(64 * sizeof(float));
    u32* ebuf = (u32*)alloc((size_t)nr * E * sizeof(u32));
    u16* sbuf = (u16*)alloc((size_t)nr * E * sizeof(u16));
    u16* cntC_in = (u16*)alloc((size_t)CHUNKS * n * sizeof(u16));
    u16* cntC_out = (u16*)alloc((size_t)OCHUNKS * n * sizeof(u16));
    int* cursorC = (int*)alloc((size_t)CHUNKS * n * sizeof(int));
    int* rowptr = (int*)alloc((size_t)(n + 1) * sizeof(int));
    int* blocksums = (int*)alloc(256 * sizeof(int));
    u16* colsrc = (u16*)alloc((size_t)E * sizeof(u16));
    float* norm_src = (float*)alloc((size_t)n * sizeof(float));
    float* norm_dst = (float*)alloc((size_t)n * sizeof(float));
    float* vsrc = (float*)alloc((size_t)n * sizeof(float));
    bf16_t* hA = (bf16_t*)alloc((size_t)n * 64 * sizeof(bf16_t));
    bf16_t* hX = (bf16_t*)alloc((size_t)n * 64 * sizeof(bf16_t));

    int gP = (E + 1023) / 1024;
    k_init<<<1, 64, 0, stream>>>(dcur, scur, gsum, ticket, E);
    k_part<<<gP, 256, 0, stream>>>(src, dst, dcur, scur, ebuf, sbuf, nr, E);
    k_hist<<<nr * CHUNKS + nr * OCHUNKS, 256, 0, stream>>>(ebuf, sbuf, dcur, scur,
                                                           cntC_in, cntC_out, nr, n, E);
    k_scan1<<<nb, 256, 0, stream>>>(cntC_in, rowptr, blocksums, n);
    k_scan3<<<nb, 256, 0, stream>>>(rowptr, blocksums, cntC_in, cntC_out,
                                    cursorC, norm_src, norm_dst, vsrc, nb, n, E);
    k_fillv2<<<nr * CHUNKS, 256, 0, stream>>>(ebuf, dcur, cursorC, colsrc, nr, n, E);

    // layer 0 (quarter-wave per node)
    k_layer0<<<(n + 15) / 16, 256, 0, stream>>>(rowptr, colsrc, vsrc, norm_dst, norm_src,
                                                W0, b0, hA, n);

    // layers 1,2: fused gather + MFMA dense; layer 2 fuses Wr-dot + graph mean + finalize
    int gfgd = (n + 63) / 64;
    k_fgd<0><<<gfgd, 256, 0, stream>>>(rowptr, colsrc, hA, norm_dst, norm_src,
                                       W1, b1, nullptr, nullptr, hX, nullptr,
                                       nullptr, nullptr, nullptr, n);
    k_fgd<1><<<gfgd, 256, 0, stream>>>(rowptr, colsrc, hX, norm_dst, nullptr,
                                       W2, b2, Wr, n2g, nullptr, gsum,
                                       ticket, br, out, n);
}

// Round 16
// 206.533 us; speedup vs baseline: 1.1980x; 1.1980x over previous
//
#include <hip/hip_runtime.h>
#include <hip/hip_bf16.h>

#define NGRAPHS 64
#define RANGE 8192
#define RSHIFT 13
#define CHUNKS 32
#define OCHUNKS 8

typedef unsigned short u16;
typedef unsigned int u32;
typedef unsigned long long u64;
typedef unsigned short bf16_t;
using s8v = __attribute__((ext_vector_type(8))) short;   // 8 bf16 (4 VGPRs)
using f4v = __attribute__((ext_vector_type(4))) float;   // MFMA accumulator

__device__ inline float bf2f(bf16_t u) { return __uint_as_float(((unsigned)u) << 16); }
__device__ inline bf16_t f2bf(float f) {
    unsigned x = __float_as_uint(f);
    return (bf16_t)((x + 0x7fffu + ((x >> 16) & 1u)) >> 16);  // RNE
}
__device__ inline void acc4(u64 v, float& a, float& b, float& c, float& d) {
    u32 lo = (u32)v, hi = (u32)(v >> 32);
    a += __uint_as_float(lo << 16);
    b += __uint_as_float(lo & 0xFFFF0000u);
    c += __uint_as_float(hi << 16);
    d += __uint_as_float(hi & 0xFFFF0000u);
}

// ============ init: bucket cursors (base r*E) + gsum zero ============
__global__ void k_init(int* __restrict__ dcur, int* __restrict__ scur,
                       float* __restrict__ gsum, int E) {
    int t = threadIdx.x;
    if (t < 16) { dcur[t] = t * E; scur[t] = t * E; }
    gsum[t] = 0.0f;
}

// ============ partition edges by dst-range (and src by src-range); LDS local rank ============
__global__ void k_part(const int* __restrict__ src, const int* __restrict__ dst,
                       int* __restrict__ dcur, int* __restrict__ scur,
                       u32* __restrict__ ebuf, u16* __restrict__ sbuf, int nr, int E) {
    __shared__ int ldc[16], lsc[16], gdb[16], gsb[16];
    int tid = threadIdx.x;
    if (tid < 16) { ldc[tid] = 0; lsc[tid] = 0; }
    __syncthreads();
    int e4 = (blockIdx.x * 256 + tid) * 4;
    int s[4], d[4], pd[4], ps[4];
    int cnt = 0;
    if (e4 + 4 <= E) {
        int4 dv = *(const int4*)&dst[e4];
        int4 sv = *(const int4*)&src[e4];
        s[0] = sv.x; s[1] = sv.y; s[2] = sv.z; s[3] = sv.w;
        d[0] = dv.x; d[1] = dv.y; d[2] = dv.z; d[3] = dv.w;
        cnt = 4;
    } else {
        for (int e = e4; e < E; ++e) { s[cnt] = src[e]; d[cnt] = dst[e]; ++cnt; }
    }
    for (int i = 0; i < cnt; ++i) {
        pd[i] = atomicAdd(&ldc[d[i] >> RSHIFT], 1);   // LDS local rank
        ps[i] = atomicAdd(&lsc[s[i] >> RSHIFT], 1);
    }
    __syncthreads();
    if (tid < nr) {
        gdb[tid] = atomicAdd(&dcur[tid], ldc[tid]);   // ~14 global atomics/block
        gsb[tid] = atomicAdd(&scur[tid], lsc[tid]);
    }
    __syncthreads();
    for (int i = 0; i < cnt; ++i) {
        int db = d[i] >> RSHIFT, sb = s[i] >> RSHIFT;
        ebuf[gdb[db] + pd[i]] = ((u32)s[i] << 16) | (u32)d[i];
        sbuf[gsb[sb] + ps[i]] = (u16)s[i];
    }
}

// ============ histogram: in (dst, CHUNKS copies) then out (src, OCHUNKS copies) ============
__global__ void k_hist(const u32* __restrict__ ebuf, const u16* __restrict__ sbuf,
                       const int* __restrict__ dcur, const int* __restrict__ scur,
                       u16* __restrict__ cntC_in, u16* __restrict__ cntC_out,
                       int nr, int n, int E) {
    __shared__ int hist[RANGE];
    int tid = threadIdx.x, bid = blockIdx.x;
    int type, r, c, nchunk;
    if (bid < nr * CHUNKS) {
        type = 0; r = bid / CHUNKS; c = bid - r * CHUNKS; nchunk = CHUNKS;
    } else {
        int rem = bid - nr * CHUNKS;
        type = 1; r = rem / OCHUNKS; c = rem - r * OCHUNKS; nchunk = OCHUNKS;
    }
    for (int i = tid; i < RANGE; i += 256) hist[i] = 0;
    __syncthreads();
    int lo = r * RANGE;
    int seg0 = r * E;
    int seg1 = type ? scur[r] : dcur[r];
    int sz = seg1 - seg0;
    int ce0 = seg0 + (int)((long long)sz * c / nchunk);
    int ce1 = seg0 + (int)((long long)sz * (c + 1) / nchunk);
    int e = ce0 + tid;
    if (type == 0) {
        for (; e + 768 < ce1; e += 1024) {
            int k0 = ebuf[e] & 0xFFFF, k1 = ebuf[e + 256] & 0xFFFF;
            int k2 = ebuf[e + 512] & 0xFFFF, k3 = ebuf[e + 768] & 0xFFFF;
            atomicAdd(&hist[k0 - lo], 1); atomicAdd(&hist[k1 - lo], 1);
            atomicAdd(&hist[k2 - lo], 1); atomicAdd(&hist[k3 - lo], 1);
        }
        for (; e < ce1; e += 256) atomicAdd(&hist[(ebuf[e] & 0xFFFF) - lo], 1);
    } else {
        for (; e + 768 < ce1; e += 1024) {
            int k0 = sbuf[e], k1 = sbuf[e + 256], k2 = sbuf[e + 512], k3 = sbuf[e + 768];
            atomicAdd(&hist[k0 - lo], 1); atomicAdd(&hist[k1 - lo], 1);
            atomicAdd(&hist[k2 - lo], 1); atomicAdd(&hist[k3 - lo], 1);
        }
        for (; e < ce1; e += 256) atomicAdd(&hist[(int)sbuf[e] - lo], 1);
    }
    __syncthreads();
    int hi = min(n - lo, RANGE);
    u16* __restrict__ outb = (type ? cntC_out : cntC_in) + (size_t)c * n + lo;
    for (int i = tid; i < hi; i += 256) outb[i] = (u16)hist[i];
}

__device__ inline int block_excl_scan(int v, int tid, int* wavesums, int* block_total) {
    int lane = tid & 63, wave = tid >> 6;
    int incl = v;
    #pragma unroll
    for (int off = 1; off < 64; off <<= 1) {
        int t = __shfl_up(incl, off);
        if (lane >= off) incl += t;
    }
    if (lane == 63) wavesums[wave] = incl;
    __syncthreads();
    int woff = 0;
    #pragma unroll
    for (int w = 0; w < 4; ++w) if (w < wave) woff += wavesums[w];
    *block_total = wavesums[0] + wavesums[1] + wavesums[2] + wavesums[3];
    return incl + woff - v;
}

__global__ void k_scan1(const u16* __restrict__ cntC_in,
                        int* __restrict__ rowptr, int* __restrict__ blocksums, int n) {
    __shared__ int wavesums[4];
    int tid = threadIdx.x;
    int idx = blockIdx.x * 256 + tid;
    int v = 0;
    if (idx < n) {
        #pragma unroll
        for (int k = 0; k < CHUNKS; ++k) v += (int)cntC_in[(size_t)k * n + idx];
    }
    int total;
    int excl = block_excl_scan(v, tid, wavesums, &total);
    if (idx < n) rowptr[idx] = excl;
    if (tid == 0) blocksums[blockIdx.x] = total;
}

// scan3 with scan2 folded in (nb <= 256); in-degree derived from cursor-base walk
__global__ void k_scan3(int* __restrict__ rowptr, const int* __restrict__ blocksums,
                        const u16* __restrict__ cntC_in, const u16* __restrict__ cntC_out,
                        int* __restrict__ cursorC,
                        float* __restrict__ norm_src, float* __restrict__ norm_dst,
                        float* __restrict__ vsrc, int nb, int n, int E) {
    __shared__ int wavesums[4];
    __shared__ int sbs[256];
    int tid = threadIdx.x;
    int bv = (tid < nb) ? blocksums[tid] : 0;
    int total;
    int bexcl = block_excl_scan(bv, tid, wavesums, &total);
    sbs[tid] = bexcl;
    __syncthreads();
    int blockoff = sbs[blockIdx.x];

    int idx = blockIdx.x * 256 + tid;
    if (idx < n) {
        int base0 = rowptr[idx] + blockoff;
        int base = base0;
        rowptr[idx] = base0;
        #pragma unroll
        for (int k = 0; k < CHUNKS; ++k) {
            cursorC[(size_t)k * n + idx] = base;
            base += (int)cntC_in[(size_t)k * n + idx];
        }
        int dout = 0;
        #pragma unroll
        for (int k = 0; k < OCHUNKS; ++k) dout += (int)cntC_out[(size_t)k * n + idx];
        float di = (float)(base - base0);
        float ns = rsqrtf(fmaxf((float)dout, 1.0f));
        norm_src[idx] = ns;
        norm_dst[idx] = rsqrtf(fmaxf(di, 1.0f));
        vsrc[idx] = di * ns;
    }
    if (idx == 0) rowptr[n] = E;
}

__global__ void k_fillv2(const u32* __restrict__ ebuf, const int* __restrict__ dcur,
                         const int* __restrict__ cursorC, u16* __restrict__ colsrc,
                         int nr, int n, int E) {
    __shared__ int cur[RANGE];
    int tid = threadIdx.x, bid = blockIdx.x;
    int r = bid / CHUNKS, c = bid - r * CHUNKS;
    int lo = r * RANGE, hi = min(n - lo, RANGE);
    for (int i = tid; i < hi; i += 256) cur[i] = cursorC[(size_t)c * n + lo + i];
    __syncthreads();
    int seg0 = r * E, seg1 = dcur[r];
    int sz = seg1 - seg0;
    int ce0 = seg0 + (int)((long long)sz * c / CHUNKS);
    int ce1 = seg0 + (int)((long long)sz * (c + 1) / CHUNKS);
    int e = ce0 + tid;
    for (; e + 768 < ce1; e += 1024) {
        u32 v0 = ebuf[e], v1 = ebuf[e + 256], v2 = ebuf[e + 512], v3 = ebuf[e + 768];
        colsrc[atomicAdd(&cur[(v0 & 0xFFFF) - lo], 1)] = (u16)(v0 >> 16);
        colsrc[atomicAdd(&cur[(v1 & 0xFFFF) - lo], 1)] = (u16)(v1 >> 16);
        colsrc[atomicAdd(&cur[(v2 & 0xFFFF) - lo], 1)] = (u16)(v2 >> 16);
        colsrc[atomicAdd(&cur[(v3 & 0xFFFF) - lo], 1)] = (u16)(v3 >> 16);
    }
    for (; e < ce1; e += 256) {
        u32 v = ebuf[e];
        colsrc[atomicAdd(&cur[(v & 0xFFFF) - lo], 1)] = (u16)(v >> 16);
    }
}

// ============ layer 0: quarter-wave per node, u64 feat stores ============
__global__ void k_layer0(const int* __restrict__ rowptr, const u16* __restrict__ colsrc,
                         const float* __restrict__ vsrc, const float* __restrict__ norm_dst,
                         const float* __restrict__ norm_src,
                         const float* __restrict__ W0, const float* __restrict__ b0,
                         bf16_t* __restrict__ out, int n) {
    int wave = threadIdx.x >> 6, lane = threadIdx.x & 63;
    int qw = lane >> 4, f = lane & 15;
    int i = blockIdx.x * 16 + wave * 4 + qw;
    if (i >= n) return;
    int p0 = rowptr[i], pe = rowptr[i + 1];
    float s = 0.0f;
    for (int p = p0 + f; p < pe; p += 16) s += vsrc[colsrc[p]];
    #pragma unroll
    for (int off = 1; off < 16; off <<= 1) s += __shfl_xor(s, off);
    float nd = norm_dst[i], ns = norm_src[i];
    float4 w = ((const float4*)W0)[f];
    float4 bb = ((const float4*)b0)[f];
    float a = s * nd;
    float v0 = fmaxf(a * w.x + bb.x, 0.0f) * ns;
    float v1 = fmaxf(a * w.y + bb.y, 0.0f) * ns;
    float v2 = fmaxf(a * w.z + bb.z, 0.0f) * ns;
    float v3 = fmaxf(a * w.w + bb.w, 0.0f) * ns;
    u32 plo = ((u32)f2bf(v1) << 16) | (u32)f2bf(v0);
    u32 phi = ((u32)f2bf(v3) << 16) | (u32)f2bf(v2);
    *(u64*)&out[(size_t)i * 64 + f * 4] = ((u64)phi << 32) | plo;
}

// ============ FUSED gather -> LDS A-strip -> MFMA dense ============
// FUSE_DOT=1: per-graph partial sums -> gsum atomics (NO threadfence — r15's
// __threadfence L2-writeback cost +45 us; cross-kernel visibility via kernel
// boundary is sufficient, finalize is a separate kernel).
template <int FUSE_DOT>
__global__ __launch_bounds__(256, 4)
void k_fgd(const int* __restrict__ rowptr, const u16* __restrict__ colsrc,
           const bf16_t* __restrict__ hin, const float* __restrict__ norm_dst,
           const float* __restrict__ norm_src,
           const float* __restrict__ W, const float* __restrict__ b,
           const float* __restrict__ Wr, const int* __restrict__ n2g,
           bf16_t* __restrict__ hout, float* __restrict__ gsum, int n) {
    __shared__ bf16_t Wbf[64 * 64];
    __shared__ float bs[64];
    __shared__ u32 astrip[64 * 36];   // 64 rows, stride 36 u32 = 144 B
    __shared__ float gacc[64];
    int tid = threadIdx.x;
    #pragma unroll
    for (int it = 0; it < 16; ++it) {
        int idx = tid + it * 256;
        Wbf[idx] = f2bf(W[idx]);
    }
    if (tid < 64) { bs[tid] = b[tid]; if (FUSE_DOT) gacc[tid] = 0.0f; }
    __syncthreads();

    int wave = tid >> 6, lane = tid & 63;
    int quad = lane >> 4, l16 = lane & 15;
    int qw = lane >> 4, f = lane & 15, qb = qw << 4;

    int m0 = (blockIdx.x * 4 + wave) * 16;
    bool active = (m0 < n);
    if (!FUSE_DOT && !active) return;

    if (active) {
        // B fragments from LDS (one-time)
        s8v bfrag[4][2];
        #pragma unroll
        for (int t = 0; t < 4; ++t)
            #pragma unroll
            for (int c = 0; c < 2; ++c)
                #pragma unroll
                for (int jj = 0; jj < 8; ++jj)
                    bfrag[t][c][jj] = (short)Wbf[(c * 32 + qw * 8 + jj) * 64 + t * 16 + l16];

        const u64* __restrict__ hp = (const u64*)hin;  // row c -> c*16 + f

        // gather 16 rows, 4 at a time (quarter-waves independent)
        for (int t = 0; t < 16; t += 4) {
            int i = m0 + t + qw;
            int p0 = 0, deg = 0;
            if (i < n) { p0 = rowptr[i]; deg = rowptr[i + 1] - p0; }
            float s0 = 0.f, s1 = 0.f, s2 = 0.f, s3 = 0.f;
            float t0 = 0.f, t1 = 0.f, t2 = 0.f, t3 = 0.f;
            for (int cb = 0; cb < deg; cb += 16) {
                int m = min(16, deg - cb);
                int col = (f < m) ? (int)colsrc[p0 + cb + f] : 0;
                int e = 0;
                for (; e + 8 <= m; e += 8) {
                    int c0 = __shfl(col, qb + e),     c1 = __shfl(col, qb + e + 1);
                    int c2 = __shfl(col, qb + e + 2), c3 = __shfl(col, qb + e + 3);
                    int c4 = __shfl(col, qb + e + 4), c5 = __shfl(col, qb + e + 5);
                    int c6 = __shfl(col, qb + e + 6), c7 = __shfl(col, qb + e + 7);
                    u64 v0 = hp[c0 * 16 + f], v1 = hp[c1 * 16 + f];
                    u64 v2 = hp[c2 * 16 + f], v3 = hp[c3 * 16 + f];
                    u64 v4 = hp[c4 * 16 + f], v5 = hp[c5 * 16 + f];
                    u64 v6 = hp[c6 * 16 + f], v7 = hp[c7 * 16 + f];
                    acc4(v0, s0, s1, s2, s3); acc4(v1, t0, t1, t2, t3);
                    acc4(v2, s0, s1, s2, s3); acc4(v3, t0, t1, t2, t3);
                    acc4(v4, s0, s1, s2, s3); acc4(v5, t0, t1, t2, t3);
                    acc4(v6, s0, s1, s2, s3); acc4(v7, t0, t1, t2, t3);
                }
                for (; e < m; ++e) {
                    int c = __shfl(col, qb + e);
                    acc4(hp[c * 16 + f], s0, s1, s2, s3);
                }
            }
            u64 packed = 0;
            if (i < n) {
                float nd = norm_dst[i];
                float f0 = (s0 + t0) * nd, f1 = (s1 + t1) * nd;
                float f2 = (s2 + t2) * nd, f3 = (s3 + t3) * nd;
                u32 plo = ((u32)f2bf(f1) << 16) | (u32)f2bf(f0);
                u32 phi = ((u32)f2bf(f3) << 16) | (u32)f2bf(f2);
                packed = ((u64)phi << 32) | plo;
            }
            *(u64*)&astrip[(wave * 16 + t + qw) * 36 + f * 2] = packed;
        }
        asm volatile("s_waitcnt lgkmcnt(0)" ::: "memory");  // wave-local LDS RAW fence

        const char* ap = (const char*)astrip + (wave * 16 + l16) * 144 + quad * 16;
        s8v a0 = *(const s8v*)ap;
        s8v a1 = *(const s8v*)(ap + 64);

        f4v acc[4];
        #pragma unroll
        for (int t = 0; t < 4; ++t) { acc[t][0] = 0.f; acc[t][1] = 0.f; acc[t][2] = 0.f; acc[t][3] = 0.f; }
        #pragma unroll
        for (int t = 0; t < 4; ++t) {
            acc[t] = __builtin_amdgcn_mfma_f32_16x16x32_bf16(a0, bfrag[t][0], acc[t], 0, 0, 0);
            acc[t] = __builtin_amdgcn_mfma_f32_16x16x32_bf16(a1, bfrag[t][1], acc[t], 0, 0, 0);
        }

        if (FUSE_DOT) {
            float p0 = 0.f, p1 = 0.f, p2 = 0.f, p3 = 0.f;
            #pragma unroll
            for (int t = 0; t < 4; ++t) {
                float wr = Wr[t * 16 + l16];
                float bias = bs[t * 16 + l16];
                p0 = fmaf(fmaxf(acc[t][0] + bias, 0.f), wr, p0);
                p1 = fmaf(fmaxf(acc[t][1] + bias, 0.f), wr, p1);
                p2 = fmaf(fmaxf(acc[t][2] + bias, 0.f), wr, p2);
                p3 = fmaf(fmaxf(acc[t][3] + bias, 0.f), wr, p3);
            }
            float pr[4] = {p0, p1, p2, p3};
            #pragma unroll
            for (int r = 0; r < 4; ++r) {
                float v = pr[r];
                v += __shfl_xor(v, 1); v += __shfl_xor(v, 2);
                v += __shfl_xor(v, 4); v += __shfl_xor(v, 8);
                int i = m0 + quad * 4 + r;
                if (l16 == 0 && i < n) atomicAdd(&gacc[n2g[i]], v);  // LDS atomic
            }
        } else {
            float ns[4];
            #pragma unroll
            for (int r = 0; r < 4; ++r) {
                int i = m0 + quad * 4 + r;
                ns[r] = norm_src[i < n ? i : n - 1];
            }
            #pragma unroll
            for (int t = 0; t < 4; ++t) {
                float bias = bs[t * 16 + l16];
                #pragma unroll
                for (int r = 0; r < 4; ++r) {
                    int i = m0 + quad * 4 + r;
                    if (i < n) {
                        float v = fmaxf(acc[t][r] + bias, 0.f) * ns[r];
                        hout[(size_t)i * 64 + t * 16 + l16] = f2bf(v);
                    }
                }
            }
        }
    }

    if (FUSE_DOT) {
        __syncthreads();
        if (tid < 64) {
            float v = gacc[tid];
            if (v != 0.0f) atomicAdd(&gsum[tid], v);   // ~2 nonzero graphs/block
        }
    }
}

// ============ finalize: out[g] = gsum[g]/count[g] + br ============
__global__ void k_fin(const float* __restrict__ gsum, const int* __restrict__ n2g,
                      const float* __restrict__ br, float* __restrict__ out, int n) {
    int g = threadIdx.x;
    int lo = 0, hi = n;
    while (lo < hi) { int mid = (lo + hi) >> 1; if (n2g[mid] < g) lo = mid + 1; else hi = mid; }
    int lo2 = lo, hi2 = n, g1 = g + 1;
    while (lo2 < hi2) { int mid = (lo2 + hi2) >> 1; if (n2g[mid] < g1) lo2 = mid + 1; else hi2 = mid; }
    out[g] = gsum[g] / fmaxf((float)(lo2 - lo), 1.0f) + br[0];
}

extern "C" void kernel_launch(void* const* d_in, const int* in_sizes, int n_in,
                              void* d_out, int out_size, void* d_ws, size_t ws_size,
                              hipStream_t stream) {
    const int* src = (const int*)d_in[0];
    const int* dst = (const int*)d_in[1];
    const int* n2g = (const int*)d_in[2];
    const float* W0 = (const float*)d_in[3];
    const float* b0 = (const float*)d_in[4];
    const float* W1 = (const float*)d_in[5];
    const float* b1 = (const float*)d_in[6];
    const float* W2 = (const float*)d_in[7];
    const float* b2 = (const float*)d_in[8];
    const float* Wr = (const float*)d_in[9];
    const float* br = (const float*)d_in[10];
    float* out = (float*)d_out;

    int E = in_sizes[0];
    int n = in_sizes[2];               // 50000 (< 65536: u16 packing valid)
    int nb = (n + 255) / 256;          // 196 (<= 256 for merged scan)
    int nr = (n + RANGE - 1) / RANGE;  // 7

    char* base = (char*)d_ws;
    size_t off = 0;
    auto alloc = [&](size_t bytes) -> void* {
        off = (off + 255) & ~(size_t)255;
        void* p = base + off;
        off += bytes;
        return p;
    };
    int* meta = (int*)alloc(64 * sizeof(int));
    int* dcur = meta;          // 16 (cursor; base r*E)
    int* scur = meta + 16;     // 16
    float* gsum = (float*)alloc(64 * sizeof(float));
    u32* ebuf = (u32*)alloc((size_t)nr * E * sizeof(u32));
    u16* sbuf = (u16*)alloc((size_t)nr * E * sizeof(u16));
    u16* cntC_in = (u16*)alloc((size_t)CHUNKS * n * sizeof(u16));
    u16* cntC_out = (u16*)alloc((size_t)OCHUNKS * n * sizeof(u16));
    int* cursorC = (int*)alloc((size_t)CHUNKS * n * sizeof(int));
    int* rowptr = (int*)alloc((size_t)(n + 1) * sizeof(int));
    int* blocksums = (int*)alloc(256 * sizeof(int));
    u16* colsrc = (u16*)alloc((size_t)E * sizeof(u16));
    float* norm_src = (float*)alloc((size_t)n * sizeof(float));
    float* norm_dst = (float*)alloc((size_t)n * sizeof(float));
    float* vsrc = (float*)alloc((size_t)n * sizeof(float));
    bf16_t* hA = (bf16_t*)alloc((size_t)n * 64 * sizeof(bf16_t));
    bf16_t* hX = (bf16_t*)alloc((size_t)n * 64 * sizeof(bf16_t));

    int gP = (E + 1023) / 1024;
    k_init<<<1, 64, 0, stream>>>(dcur, scur, gsum, E);
    k_part<<<gP, 256, 0, stream>>>(src, dst, dcur, scur, ebuf, sbuf, nr, E);
    k_hist<<<nr * CHUNKS + nr * OCHUNKS, 256, 0, stream>>>(ebuf, sbuf, dcur, scur,
                                                           cntC_in, cntC_out, nr, n, E);
    k_scan1<<<nb, 256, 0, stream>>>(cntC_in, rowptr, blocksums, n);
    k_scan3<<<nb, 256, 0, stream>>>(rowptr, blocksums, cntC_in, cntC_out,
                                    cursorC, norm_src, norm_dst, vsrc, nb, n, E);
    k_fillv2<<<nr * CHUNKS, 256, 0, stream>>>(ebuf, dcur, cursorC, colsrc, nr, n, E);

    // layer 0 (quarter-wave per node)
    k_layer0<<<(n + 15) / 16, 256, 0, stream>>>(rowptr, colsrc, vsrc, norm_dst, norm_src,
                                                W0, b0, hA, n);

    // layers 1,2: fused gather + MFMA dense; layer 2 fuses Wr-dot + graph partial sums
    int gfgd = (n + 63) / 64;
    k_fgd<0><<<gfgd, 256, 0, stream>>>(rowptr, colsrc, hA, norm_dst, norm_src,
                                       W1, b1, nullptr, nullptr, hX, nullptr, n);
    k_fgd<1><<<gfgd, 256, 0, stream>>>(rowptr, colsrc, hX, norm_dst, nullptr,
                                       W2, b2, Wr, n2g, nullptr, gsum, n);

    // finalize
    k_fin<<<1, 64, 0, stream>>>(gsum, n2g, br, out, n);
}